// Round 5
// baseline (282.737 us; speedup 1.0000x reference)
//
#include <hip/hip_runtime.h>
#include <hip/hip_bf16.h>
#include <stdint.h>

namespace {

// Problem constants: B=4, C=64, H=W=256, N=65536, NQ=N/C=1024
// workspace byte offsets
constexpr size_t OFF_G     = 0;          // [4][64][64] f32
constexpr size_t OFF_S     = 65536;      // [4][64] f32
constexpr size_t OFF_M     = 66560;      // Mt [4][64k][64r] f32 (transposed M)
constexpr size_t OFF_AB    = 132096;     // [4][64] f32
constexpr size_t OFF_SCALE = 133120;     // scaleA[64], shiftB[64] f32
constexpr size_t OFF_STATS = 133632;     // sum[64], sumsq[64] f32 (atomic accum, memset to 0)
constexpr size_t OFF_WWT   = 134144;     // [64][64] f32  (w_w transposed: [c][o])
constexpr size_t OFF_WSUM  = 150528;     // [64] f32
constexpr size_t OFF_SPART = 150784;     // [4][256][64] f32   rowsum partials
constexpr size_t OFF_GPART = 412928;     // [4][256][4096] f32 gram partials
constexpr size_t OFF_V     = 17190144;   // [4][64o][64k][1024q] bf16
constexpr size_t OFF_WY    = 50744576;   // [4][64][65536] bf16
// total ws needed: 84299008 bytes (~80.4 MB)

__device__ __forceinline__ float bf2f(unsigned short u) {
    return __uint_as_float(((unsigned)u) << 16);
}
__device__ __forceinline__ unsigned short f2bf(float f) {
    union { __hip_bfloat16 h; unsigned short u; } cv;
    cv.h = __float2bfloat16(f);
    return cv.u;
}
__device__ __forceinline__ unsigned pack2bf(float a, float b) {
    return (unsigned)f2bf(a) | ((unsigned)f2bf(b) << 16);
}

// ---------------------------------------------------------------------------
// k_trans: WwT[c][o] = Ww[o][c]; Wsum[o] = sum_c Ww[o][c]
__global__ __launch_bounds__(256) void k_trans(const float* __restrict__ Ww,
                                               float* __restrict__ WwT,
                                               float* __restrict__ Wsum) {
    const int t = threadIdx.x;
    for (int e = t; e < 4096; e += 256) {
        const int o = e >> 6, c = e & 63;
        WwT[c * 64 + o] = Ww[e];
    }
    if (t < 64) {
        float s = 0.f;
#pragma unroll 8
        for (int c = 0; c < 64; ++c) s += Ww[t * 64 + c];
        Wsum[t] = s;
    }
}

// ---------------------------------------------------------------------------
// k_gram: per (batch, 256-column chunk) partial of G = X X^T and s = X @ 1.
__global__ __launch_bounds__(128) void k_gram(const float* __restrict__ x,
                                              float* __restrict__ gpart,
                                              float* __restrict__ spart) {
    const int wg = blockIdx.x;     // 0..1023
    const int b = wg >> 8;
    const int chunk = wg & 255;
    const int t = threadIdx.x;
    const int wv = t >> 6;
    const int l = t & 63;
    const int g = l >> 3, h = l & 7;

    __shared__ __align__(16) float tile[64][64];
    __shared__ __align__(16) float Gred[4096];

    float acc[8][8];
#pragma unroll
    for (int i = 0; i < 8; ++i)
#pragma unroll
        for (int j = 0; j < 8; ++j) acc[i][j] = 0.f;
    float sp[8];
#pragma unroll
    for (int i = 0; i < 8; ++i) sp[i] = 0.f;

    const float* xb = x + (size_t)b * 64 * 65536 + chunk * 256;

    for (int t4 = 0; t4 < 4; ++t4) {
#pragma unroll
        for (int it = 0; it < 8; ++it) {
            const int v = it * 128 + t;
            const int row = v >> 4;
            const int c4 = v & 15;
            const float4 val = *(const float4*)(xb + (size_t)row * 65536 + t4 * 64 + c4 * 4);
            const int c4s = c4 ^ (row >> 3);
            *(float4*)&tile[row][c4s * 4] = val;
            sp[it] += val.x + val.y + val.z + val.w;
        }
        __syncthreads();
        const int fbase = wv * 8;
#pragma unroll
        for (int fs = 0; fs < 8; ++fs) {
            const int f = fbase + fs;
            float4 a4[8], b4[8];
#pragma unroll
            for (int i = 0; i < 8; ++i) a4[i] = *(const float4*)&tile[g * 8 + i][(f ^ g) * 4];
#pragma unroll
            for (int j = 0; j < 8; ++j) b4[j] = *(const float4*)&tile[h * 8 + j][(f ^ h) * 4];
#pragma unroll
            for (int i = 0; i < 8; ++i)
#pragma unroll
                for (int j = 0; j < 8; ++j) {
                    acc[i][j] += a4[i].x * b4[j].x;
                    acc[i][j] += a4[i].y * b4[j].y;
                    acc[i][j] += a4[i].z * b4[j].z;
                    acc[i][j] += a4[i].w * b4[j].w;
                }
        }
        __syncthreads();
    }

    if (wv == 1) {
#pragma unroll
        for (int i = 0; i < 8; ++i)
#pragma unroll
            for (int j4 = 0; j4 < 2; ++j4) {
                float4 v;
                v.x = acc[i][j4 * 4 + 0]; v.y = acc[i][j4 * 4 + 1];
                v.z = acc[i][j4 * 4 + 2]; v.w = acc[i][j4 * 4 + 3];
                *(float4*)&Gred[(g * 8 + i) * 64 + h * 8 + j4 * 4] = v;
            }
    }
    __syncthreads();
    if (wv == 0) {
        float* gp = gpart + (size_t)wg * 4096;
#pragma unroll
        for (int i = 0; i < 8; ++i)
#pragma unroll
            for (int j4 = 0; j4 < 2; ++j4) {
                const float4 r = *(const float4*)&Gred[(g * 8 + i) * 64 + h * 8 + j4 * 4];
                float4 v;
                v.x = acc[i][j4 * 4 + 0] + r.x; v.y = acc[i][j4 * 4 + 1] + r.y;
                v.z = acc[i][j4 * 4 + 2] + r.z; v.w = acc[i][j4 * 4 + 3] + r.w;
                *(float4*)(gp + (g * 8 + i) * 64 + h * 8 + j4 * 4) = v;
            }
    }
#pragma unroll
    for (int it = 0; it < 8; ++it) {
        float v = sp[it];
        v += __shfl_xor(v, 1);
        v += __shfl_xor(v, 2);
        v += __shfl_xor(v, 4);
        v += __shfl_xor(v, 8);
        if ((l & 15) == 0) {
            const int row = it * 8 + (t >> 4);
            spart[((size_t)b * 256 + chunk) * 64 + row] = v;
        }
    }
}

// ---------------------------------------------------------------------------
// k_gred: G[b] = sum over 256 chunk partials; s[b] likewise.
__global__ __launch_bounds__(256) void k_gred(const float* __restrict__ gpart,
                                              const float* __restrict__ spart,
                                              float* __restrict__ G,
                                              float* __restrict__ s) {
    const int b = blockIdx.x >> 4;
    const int part = blockIdx.x & 15;
    const int t = threadIdx.x;
    const int e4l = t & 63;
    const int cg = t >> 6;                  // wave id 0..3
    const int e4 = part * 64 + e4l;
    const float4* gp4 = (const float4*)gpart;

    float4 a = make_float4(0.f, 0.f, 0.f, 0.f);
#pragma unroll 8
    for (int i = 0; i < 64; ++i) {
        const int w = cg * 64 + i;
        const float4 v = gp4[((size_t)b * 256 + w) * 1024 + e4];
        a.x += v.x; a.y += v.y; a.z += v.z; a.w += v.w;
    }
    __shared__ __align__(16) float4 red[4][64];
    __shared__ float reds[4][64];
    red[cg][e4l] = a;

    float sv = 0.f;
    if (part == 0) {
#pragma unroll 8
        for (int i = 0; i < 64; ++i) {
            const int w = cg * 64 + i;
            sv += spart[((size_t)b * 256 + w) * 64 + e4l];
        }
        reds[cg][e4l] = sv;
    }
    __syncthreads();
    if (cg == 0) {
        const float4 r1 = red[1][e4l], r2 = red[2][e4l], r3 = red[3][e4l];
        float4 o;
        o.x = a.x + r1.x + r2.x + r3.x;
        o.y = a.y + r1.y + r2.y + r3.y;
        o.z = a.z + r1.z + r2.z + r3.z;
        o.w = a.w + r1.w + r2.w + r3.w;
        *(float4*)(G + (size_t)b * 4096 + (size_t)e4 * 4) = o;
        if (part == 0) {
            s[b * 64 + e4l] = sv + reds[1][e4l] + reds[2][e4l] + reds[3][e4l];
        }
    }
}

// ---------------------------------------------------------------------------
// k_small: f = Pw G Tw^T + rank-1 terms; attn = softmax; Mt = (attn@Gw)^T; ab.
__global__ __launch_bounds__(256) void k_small(const float* __restrict__ G,
                                               const float* __restrict__ s,
                                               const float* __restrict__ Pw,
                                               const float* __restrict__ pb,
                                               const float* __restrict__ Tw,
                                               const float* __restrict__ tb,
                                               const float* __restrict__ Gw,
                                               const float* __restrict__ gb,
                                               float* __restrict__ Mt,
                                               float* __restrict__ ab) {
    const int b = blockIdx.x >> 1;
    const int rblk = (blockIdx.x & 1) * 32;
    const int t = threadIdx.x;
    const int rl = t >> 3;
    const int seg = t & 7;
    const int d0 = seg * 8;
    const int rg = rblk + rl;

    __shared__ __align__(16) float GL[64][68];
    __shared__ __align__(16) float TwL[64][68];
    __shared__ __align__(16) float GwL[64][68];
    __shared__ __align__(16) float PwL[32][68];
    __shared__ __align__(16) float AL[32][68];
    __shared__ __align__(16) float atL[32][68];
    __shared__ float sL[64], TsL[64], PsL[32], pbL[64], tbL[64], gbL[64];

    for (int v = t; v < 1024; v += 256) {
        const int k = v >> 4, c4 = (v & 15) * 4;
        *(float4*)&GL[k][c4]  = *(const float4*)(G + (size_t)b * 4096 + (size_t)v * 4);
        *(float4*)&TwL[k][c4] = *(const float4*)(Tw + (size_t)v * 4);
        *(float4*)&GwL[k][c4] = *(const float4*)(Gw + (size_t)v * 4);
    }
    for (int v = t; v < 512; v += 256) {
        const int k = v >> 4, c4 = (v & 15) * 4;
        *(float4*)&PwL[k][c4] = *(const float4*)(Pw + (size_t)(rblk + k) * 64 + c4);
    }
    if (t < 64) {
        sL[t] = s[b * 64 + t];
        pbL[t] = pb[t]; tbL[t] = tb[t]; gbL[t] = gb[t];
    }
    __syncthreads();
    if (t < 64) {
        float a = 0.f;
#pragma unroll 8
        for (int k = 0; k < 64; ++k) a += TwL[t][k] * sL[k];
        TsL[t] = a;
    }
    if (t < 32) {
        float a = 0.f;
#pragma unroll 8
        for (int k = 0; k < 64; ++k) a += PwL[t][k] * sL[k];
        PsL[t] = a;
    }
    {
        float4 a1 = make_float4(0.f, 0.f, 0.f, 0.f), a2 = make_float4(0.f, 0.f, 0.f, 0.f);
#pragma unroll 4
        for (int k = 0; k < 64; ++k) {
            const float pw = PwL[rl][k];
            const float4 g1 = *(const float4*)&GL[k][d0];
            const float4 g2 = *(const float4*)&GL[k][d0 + 4];
            a1.x += pw * g1.x; a1.y += pw * g1.y; a1.z += pw * g1.z; a1.w += pw * g1.w;
            a2.x += pw * g2.x; a2.y += pw * g2.y; a2.z += pw * g2.z; a2.w += pw * g2.w;
        }
        *(float4*)&AL[rl][d0] = a1;
        *(float4*)&AL[rl][d0 + 4] = a2;
    }
    __syncthreads();
    float4 areg[16];
#pragma unroll
    for (int i = 0; i < 16; ++i) areg[i] = *(const float4*)&AL[rl][i * 4];
    float fv[8];
#pragma unroll
    for (int dd = 0; dd < 8; ++dd) {
        const int d = d0 + dd;
        float4 a4 = make_float4(0.f, 0.f, 0.f, 0.f);
#pragma unroll
        for (int i = 0; i < 16; ++i) {
            const float4 tw = *(const float4*)&TwL[d][i * 4];
            a4.x += areg[i].x * tw.x; a4.y += areg[i].y * tw.y;
            a4.z += areg[i].z * tw.z; a4.w += areg[i].w * tw.w;
        }
        const float dot = (a4.x + a4.y) + (a4.z + a4.w);
        fv[dd] = dot + PsL[rl] * tbL[d] + pbL[rg] * (TsL[d] + 65536.f * tbL[d]);
    }
    float mx = fv[0];
#pragma unroll
    for (int dd = 1; dd < 8; ++dd) mx = fmaxf(mx, fv[dd]);
    mx = fmaxf(mx, __shfl_xor(mx, 1));
    mx = fmaxf(mx, __shfl_xor(mx, 2));
    mx = fmaxf(mx, __shfl_xor(mx, 4));
    float sm = 0.f;
#pragma unroll
    for (int dd = 0; dd < 8; ++dd) { fv[dd] = __expf(fv[dd] - mx); sm += fv[dd]; }
    sm += __shfl_xor(sm, 1);
    sm += __shfl_xor(sm, 2);
    sm += __shfl_xor(sm, 4);
    const float inv = 1.f / sm;
    float4 p1, p2;
    p1.x = fv[0] * inv; p1.y = fv[1] * inv; p1.z = fv[2] * inv; p1.w = fv[3] * inv;
    p2.x = fv[4] * inv; p2.y = fv[5] * inv; p2.z = fv[6] * inv; p2.w = fv[7] * inv;
    *(float4*)&atL[rl][d0] = p1;
    *(float4*)&atL[rl][d0 + 4] = p2;
    __syncthreads();
#pragma unroll
    for (int i = 0; i < 16; ++i) areg[i] = *(const float4*)&atL[rl][i * 4];
    float4 m1 = make_float4(0.f, 0.f, 0.f, 0.f), m2 = make_float4(0.f, 0.f, 0.f, 0.f);
    float abv = 0.f;
#pragma unroll
    for (int d4 = 0; d4 < 16; ++d4) {
        const float4 a = areg[d4];
#define MSTEP(comp, dc) { \
        const int d = d4 * 4 + dc; \
        const float ad = a.comp; \
        const float4 g1 = *(const float4*)&GwL[d][d0]; \
        const float4 g2 = *(const float4*)&GwL[d][d0 + 4]; \
        m1.x += ad * g1.x; m1.y += ad * g1.y; m1.z += ad * g1.z; m1.w += ad * g1.w; \
        m2.x += ad * g2.x; m2.y += ad * g2.y; m2.z += ad * g2.z; m2.w += ad * g2.w; \
        abv += ad * gbL[d]; }
        MSTEP(x, 0) MSTEP(y, 1) MSTEP(z, 2) MSTEP(w, 3)
#undef MSTEP
    }
    // store TRANSPOSED: Mt[b][k][r] = (attn@Gw)[r][k]
    float mv[8] = {m1.x, m1.y, m1.z, m1.w, m2.x, m2.y, m2.z, m2.w};
    float* Mb = Mt + (size_t)b * 4096;
#pragma unroll
    for (int dd = 0; dd < 8; ++dd) Mb[(d0 + dd) * 64 + rg] = mv[dd];
    if (seg == 0) ab[b * 64 + rg] = abv;
}

// ---------------------------------------------------------------------------
// k_convV: V[b,o,k,q] = sum_c Ww[o,c] * x[b,k,c*1024+q]   (bf16 out)
// Grid 512 = (b, k, q-half). 4 waves; wave -> 16 o, thread -> 8 q.
// Ratio fix: per c-iter = 2 float4 x-loads + 4 broadcast ds_read + 128 FMA
// -> VALU-bound (LDS pipe per CU ~384cyc < VALU ~530cyc per iter).
__global__ __launch_bounds__(256) void k_convV(const float* __restrict__ x,
                                               const float* __restrict__ WwT,
                                               unsigned short* __restrict__ V) {
    const int bid = blockIdx.x;            // (b<<7)|(k<<1)|qh
    const int b = bid >> 7;
    const int k = (bid >> 1) & 63;
    const int qh = bid & 1;
    const int t = threadIdx.x;
    const int wv = t >> 6;
    const int l = t & 63;
    const int q0 = qh * 512 + l * 8;
    const int o0 = wv * 16;

    __shared__ __align__(16) float WL[64][64];
    {
        const float4* src = (const float4*)WwT;
        float4* dst = (float4*)&WL[0][0];
#pragma unroll
        for (int i = 0; i < 4; ++i) dst[i * 256 + t] = src[i * 256 + t];
    }
    __syncthreads();

    const float* xb = x + ((size_t)b * 64 + k) * 65536 + q0;
    float acc[16][8];
#pragma unroll
    for (int i = 0; i < 16; ++i)
#pragma unroll
        for (int j = 0; j < 8; ++j) acc[i][j] = 0.f;

#pragma unroll 2
    for (int c = 0; c < 64; ++c) {
        const float4 x1 = *(const float4*)(xb + (size_t)c * 1024);
        const float4 x2 = *(const float4*)(xb + (size_t)c * 1024 + 4);
        const float xv[8] = {x1.x, x1.y, x1.z, x1.w, x2.x, x2.y, x2.z, x2.w};
        const float4* wp = (const float4*)&WL[c][o0];
        const float4 w0 = wp[0], w1 = wp[1], w2 = wp[2], w3 = wp[3];
        const float wv16[16] = {w0.x, w0.y, w0.z, w0.w, w1.x, w1.y, w1.z, w1.w,
                                w2.x, w2.y, w2.z, w2.w, w3.x, w3.y, w3.z, w3.w};
#pragma unroll
        for (int i = 0; i < 16; ++i) {
            const float w = wv16[i];
#pragma unroll
            for (int j = 0; j < 8; ++j) acc[i][j] += w * xv[j];
        }
    }
    // store: V[b][o0+i][k][q0..q0+8)  -- fully coalesced uint4 per o
    unsigned short* vb = V + (((size_t)b * 64 + o0) * 64 + k) * 1024 + q0;
#pragma unroll
    for (int i = 0; i < 16; ++i) {
        uint4 pk;
        pk.x = pack2bf(acc[i][0], acc[i][1]);
        pk.y = pack2bf(acc[i][2], acc[i][3]);
        pk.z = pack2bf(acc[i][4], acc[i][5]);
        pk.w = pack2bf(acc[i][6], acc[i][7]);
        *(uint4*)(vb + (size_t)i * 65536) = pk;
    }
}

// ---------------------------------------------------------------------------
// k_wy: w_y[b,o,q*64+r] = sum_k Mt[b,k,r] V[b,o,k,q] + Wsum[o]*ab[b,r] + wb[o]
// Grid 512 = (b, o, q-half). 4 waves; wave -> 16 r, thread -> 8 q.
// Same ratio fix: per k-iter = 1 uint4 V-load + 4 broadcast ds_read + 128 FMA.
__global__ __launch_bounds__(256) void k_wy(const unsigned short* __restrict__ V,
                                            const float* __restrict__ Mt,
                                            const float* __restrict__ ab,
                                            const float* __restrict__ Wsum,
                                            const float* __restrict__ wb,
                                            unsigned short* __restrict__ wy,
                                            float* __restrict__ stats) {
    const int bid = blockIdx.x;            // (b<<7)|(o<<1)|qh
    const int b = bid >> 7;
    const int o = (bid >> 1) & 63;
    const int qh = bid & 1;
    const int t = threadIdx.x;
    const int wv = t >> 6;
    const int l = t & 63;
    const int q0 = qh * 512 + l * 8;
    const int r0 = wv * 16;

    __shared__ __align__(16) float MtL[64][64];
    {
        const float4* src = (const float4*)(Mt + (size_t)b * 4096);
        float4* dst = (float4*)&MtL[0][0];
#pragma unroll
        for (int i = 0; i < 4; ++i) dst[i * 256 + t] = src[i * 256 + t];
    }
    __syncthreads();

    const unsigned short* vbase = V + ((size_t)b * 64 + o) * 65536 + q0;
    float acc[16][8];
#pragma unroll
    for (int i = 0; i < 16; ++i)
#pragma unroll
        for (int j = 0; j < 8; ++j) acc[i][j] = 0.f;

#pragma unroll 2
    for (int k = 0; k < 64; ++k) {
        const uint4 u = *(const uint4*)(vbase + (size_t)k * 1024);
        float v[8];
        v[0] = __uint_as_float(u.x << 16);
        v[1] = __uint_as_float(u.x & 0xffff0000u);
        v[2] = __uint_as_float(u.y << 16);
        v[3] = __uint_as_float(u.y & 0xffff0000u);
        v[4] = __uint_as_float(u.z << 16);
        v[5] = __uint_as_float(u.z & 0xffff0000u);
        v[6] = __uint_as_float(u.w << 16);
        v[7] = __uint_as_float(u.w & 0xffff0000u);
        const float4* mp = (const float4*)&MtL[k][r0];
        const float4 m0 = mp[0], m1 = mp[1], m2 = mp[2], m3 = mp[3];
        const float mv16[16] = {m0.x, m0.y, m0.z, m0.w, m1.x, m1.y, m1.z, m1.w,
                                m2.x, m2.y, m2.z, m2.w, m3.x, m3.y, m3.z, m3.w};
#pragma unroll
        for (int i = 0; i < 16; ++i) {
            const float m = mv16[i];
#pragma unroll
            for (int j = 0; j < 8; ++j) acc[i][j] += m * v[j];
        }
    }

    const float wsum_o = Wsum[o];
    const float wb_o = wb[o];
    const float* abb = ab + (size_t)b * 64 + r0;
    float addv[16];
#pragma unroll
    for (int i = 0; i < 16; ++i) addv[i] = wsum_o * abb[i] + wb_o;

    float ssum = 0.f, ssq = 0.f;
#pragma unroll
    for (int i = 0; i < 16; ++i)
#pragma unroll
        for (int j = 0; j < 8; ++j) {
            const float val = acc[i][j] + addv[i];
            acc[i][j] = val;
            ssum += val;
            ssq += val * val;
        }

    // store: for each q (j), 16 consecutive r -> 2x uint4
    unsigned short* wyb = wy + ((size_t)b * 64 + o) * 65536 + (size_t)q0 * 64 + r0;
#pragma unroll
    for (int j = 0; j < 8; ++j) {
        uint4 p1, p2;
        p1.x = pack2bf(acc[0][j],  acc[1][j]);
        p1.y = pack2bf(acc[2][j],  acc[3][j]);
        p1.z = pack2bf(acc[4][j],  acc[5][j]);
        p1.w = pack2bf(acc[6][j],  acc[7][j]);
        p2.x = pack2bf(acc[8][j],  acc[9][j]);
        p2.y = pack2bf(acc[10][j], acc[11][j]);
        p2.z = pack2bf(acc[12][j], acc[13][j]);
        p2.w = pack2bf(acc[14][j], acc[15][j]);
        *(uint4*)(wyb + (size_t)j * 64) = p1;
        *(uint4*)(wyb + (size_t)j * 64 + 8) = p2;
    }

    float v1 = ssum, v2 = ssq;
#pragma unroll
    for (int off = 1; off < 64; off <<= 1) {
        v1 += __shfl_xor(v1, off);
        v2 += __shfl_xor(v2, off);
    }
    if ((t & 63) == 0) {
        atomicAdd(&stats[o], v1);
        atomicAdd(&stats[64 + o], v2);
    }
}

// ---------------------------------------------------------------------------
__global__ __launch_bounds__(64) void k_statfin(const float* __restrict__ stats,
                                                const float* __restrict__ gamma,
                                                const float* __restrict__ beta,
                                                float* __restrict__ scaleA,
                                                float* __restrict__ shiftB) {
    const int o = threadIdx.x;
    const float invn = 1.f / 262144.f;
    const float mean = stats[o] * invn;
    const float var = stats[64 + o] * invn - mean * mean;
    const float sA = gamma[o] * rsqrtf(var + 1e-5f);
    scaleA[o] = sA;
    shiftB[o] = beta[o] - mean * sA;
}

// ---------------------------------------------------------------------------
// k_out: out = wy*scaleA[o] + shiftB[o] + x   (8 elems/thread-iter)
__global__ __launch_bounds__(256) void k_out(const unsigned short* __restrict__ wy,
                                             const float* __restrict__ x,
                                             const float* __restrict__ scaleA,
                                             const float* __restrict__ shiftB,
                                             float* __restrict__ out) {
    const size_t stride = (size_t)gridDim.x * blockDim.x;
    for (size_t i8 = (size_t)blockIdx.x * blockDim.x + threadIdx.x; i8 < 2097152; i8 += stride) {
        const size_t base = i8 * 8;
        const int o = (int)((base >> 16) & 63);
        const uint4 u = *(const uint4*)(wy + base);
        const float4 x1 = *(const float4*)(x + base);
        const float4 x2 = *(const float4*)(x + base + 4);
        const float a = scaleA[o];
        const float c = shiftB[o];
        float4 o1, o2;
        o1.x = __uint_as_float(u.x << 16) * a + c + x1.x;
        o1.y = __uint_as_float(u.x & 0xffff0000u) * a + c + x1.y;
        o1.z = __uint_as_float(u.y << 16) * a + c + x1.z;
        o1.w = __uint_as_float(u.y & 0xffff0000u) * a + c + x1.w;
        o2.x = __uint_as_float(u.z << 16) * a + c + x2.x;
        o2.y = __uint_as_float(u.z & 0xffff0000u) * a + c + x2.y;
        o2.z = __uint_as_float(u.w << 16) * a + c + x2.z;
        o2.w = __uint_as_float(u.w & 0xffff0000u) * a + c + x2.w;
        *(float4*)(out + base) = o1;
        *(float4*)(out + base + 4) = o2;
    }
}

} // namespace

extern "C" void kernel_launch(void* const* d_in, const int* in_sizes, int n_in,
                              void* d_out, int out_size, void* d_ws, size_t ws_size,
                              hipStream_t stream) {
    const float* x        = (const float*)d_in[0];
    const float* theta_w  = (const float*)d_in[1];
    const float* theta_b  = (const float*)d_in[2];
    const float* phi_w    = (const float*)d_in[3];
    const float* phi_b    = (const float*)d_in[4];
    const float* g_w      = (const float*)d_in[5];
    const float* g_b      = (const float*)d_in[6];
    const float* w_w      = (const float*)d_in[7];
    const float* w_b      = (const float*)d_in[8];
    const float* bn_gamma = (const float*)d_in[9];
    const float* bn_beta  = (const float*)d_in[10];
    float* out = (float*)d_out;
    char* ws = (char*)d_ws;

    float* G      = (float*)(ws + OFF_G);
    float* s      = (float*)(ws + OFF_S);
    float* Mt     = (float*)(ws + OFF_M);
    float* ab     = (float*)(ws + OFF_AB);
    float* scaleA = (float*)(ws + OFF_SCALE);
    float* shiftB = scaleA + 64;
    float* stats  = (float*)(ws + OFF_STATS);
    float* WwT    = (float*)(ws + OFF_WWT);
    float* Wsum   = (float*)(ws + OFF_WSUM);
    float* spart  = (float*)(ws + OFF_SPART);
    float* gpart  = (float*)(ws + OFF_GPART);
    unsigned short* V  = (unsigned short*)(ws + OFF_V);
    unsigned short* wy = (unsigned short*)(ws + OFF_WY);

    (void)in_sizes; (void)n_in; (void)out_size; (void)ws_size;

    hipMemsetAsync(stats, 0, 512, stream);
    hipLaunchKernelGGL(k_trans, dim3(1), dim3(256), 0, stream, w_w, WwT, Wsum);
    hipLaunchKernelGGL(k_gram, dim3(1024), dim3(128), 0, stream, x, gpart, spart);
    hipLaunchKernelGGL(k_gred, dim3(64), dim3(256), 0, stream, gpart, spart, G, s);
    hipLaunchKernelGGL(k_small, dim3(8), dim3(256), 0, stream, G, s, phi_w, phi_b,
                       theta_w, theta_b, g_w, g_b, Mt, ab);
    hipLaunchKernelGGL(k_convV, dim3(512), dim3(256), 0, stream, x, WwT, V);
    hipLaunchKernelGGL(k_wy, dim3(512), dim3(256), 0, stream, V, Mt, ab, Wsum, w_b, wy, stats);
    hipLaunchKernelGGL(k_statfin, dim3(1), dim3(64), 0, stream, stats, bn_gamma, bn_beta,
                       scaleA, shiftB);
    hipLaunchKernelGGL(k_out, dim3(2048), dim3(256), 0, stream, wy, x, scaleA, shiftB, out);
}

// Round 6
// 278.441 us; speedup vs baseline: 1.0154x; 1.0154x over previous
//
#include <hip/hip_runtime.h>
#include <hip/hip_bf16.h>
#include <stdint.h>

namespace {

// Problem constants: B=4, C=64, H=W=256, N=65536, NQ=N/C=1024
// workspace byte offsets
constexpr size_t OFF_G     = 0;          // [4][64][64] f32
constexpr size_t OFF_S     = 65536;      // [4][64] f32
constexpr size_t OFF_M     = 66560;      // Mt [4][64k][64r] f32 (transposed M)
constexpr size_t OFF_AB    = 132096;     // [4][64] f32
constexpr size_t OFF_SCALE = 133120;     // scaleA[64], shiftB[64] f32
constexpr size_t OFF_STATS = 133632;     // sum[64], sumsq[64] f32 (atomic accum, memset to 0)
constexpr size_t OFF_WWT   = 134144;     // [64][64] f32  (w_w transposed: [c][o])
constexpr size_t OFF_WSUM  = 150528;     // [64] f32
constexpr size_t OFF_SPART = 150784;     // [4][256][64] f32   rowsum partials
constexpr size_t OFF_GPART = 412928;     // [4][256][4096] f32 gram partials
constexpr size_t OFF_V     = 17190144;   // [4][64o][64k][1024q] bf16
constexpr size_t OFF_WY    = 50744576;   // [4][64][65536] bf16
// total ws needed: 84299008 bytes (~80.4 MB)

typedef __attribute__((ext_vector_type(8))) short bf16x8;
typedef __attribute__((ext_vector_type(4))) float f32x4;

__device__ __forceinline__ float bf2f(unsigned short u) {
    return __uint_as_float(((unsigned)u) << 16);
}
__device__ __forceinline__ unsigned short f2bf(float f) {
    union { __hip_bfloat16 h; unsigned short u; } cv;
    cv.h = __float2bfloat16(f);
    return cv.u;
}
__device__ __forceinline__ unsigned pack2bf(float a, float b) {
    return (unsigned)f2bf(a) | ((unsigned)f2bf(b) << 16);
}

// load 8 consecutive fp32, split into bf16 hi/lo fragments, fp32 running sum
__device__ __forceinline__ void loadcvt(const float* __restrict__ p,
                                        bf16x8& hi, bf16x8& lo, float& sum) {
    const float4 v1 = *(const float4*)p;
    const float4 v2 = *(const float4*)(p + 4);
    const float f[8] = {v1.x, v1.y, v1.z, v1.w, v2.x, v2.y, v2.z, v2.w};
    float s = 0.f;
#pragma unroll
    for (int j = 0; j < 8; ++j) {
        s += f[j];
        const unsigned short h = f2bf(f[j]);
        hi[j] = (short)h;
        lo[j] = (short)f2bf(f[j] - bf2f(h));
    }
    sum = s;
}

// ---------------------------------------------------------------------------
// k_trans: WwT[c][o] = Ww[o][c]; Wsum[o] = sum_c Ww[o][c]
__global__ __launch_bounds__(256) void k_trans(const float* __restrict__ Ww,
                                               float* __restrict__ WwT,
                                               float* __restrict__ Wsum) {
    const int t = threadIdx.x;
    for (int e = t; e < 4096; e += 256) {
        const int o = e >> 6, c = e & 63;
        WwT[c * 64 + o] = Ww[e];
    }
    if (t < 64) {
        float s = 0.f;
#pragma unroll 8
        for (int c = 0; c < 64; ++c) s += Ww[t * 64 + c];
        Wsum[t] = s;
    }
}

// ---------------------------------------------------------------------------
// k_gram (MFMA): per (batch, 256-col chunk) partial of G = X X^T and s = X@1.
// bf16 hi/lo split: G = Xhi Xhi^T + Xhi Xlo^T + Xlo Xhi^T (lo*lo dropped,
// ~2^-16 rel). 4 waves = 4 output quadrants (wr,wc), 2x2 tiles of 16x16 each.
// A/B fragments load DIRECTLY from global (identical lane layout: row/col =
// l&15, k = (l>>4)*8+j; 4 lanes cover 128B contiguous per row -> full
// cachelines). No LDS, no barriers. Any consistent lane->k map is valid for
// a gram (sum is permutation-invariant over k).
__global__ __launch_bounds__(256) void k_gram(const float* __restrict__ x,
                                              float* __restrict__ gpart,
                                              float* __restrict__ spart) {
    const int wg = blockIdx.x;     // 0..1023 = (b<<8)|chunk
    const int b = wg >> 8;
    const int chunk = wg & 255;
    const int t = threadIdx.x;
    const int w = t >> 6;          // wave 0..3
    const int l = t & 63;
    const int wr = w >> 1, wc = w & 1;
    const int lr = l & 15;         // row/col within tile
    const int lk = l >> 4;         // k-chunk 0..3 (8 floats each)

    const float* xb = x + (size_t)b * 64 * 65536 + chunk * 256 + lk * 8;
    const float* pa0 = xb + (size_t)(wr * 32 + lr) * 65536;
    const float* pa1 = xb + (size_t)(wr * 32 + 16 + lr) * 65536;
    const float* pb0 = xb + (size_t)(wc * 32 + lr) * 65536;
    const float* pb1 = xb + (size_t)(wc * 32 + 16 + lr) * 65536;

    f32x4 acc00 = {0.f, 0.f, 0.f, 0.f};
    f32x4 acc01 = {0.f, 0.f, 0.f, 0.f};
    f32x4 acc10 = {0.f, 0.f, 0.f, 0.f};
    f32x4 acc11 = {0.f, 0.f, 0.f, 0.f};
    float sA0 = 0.f, sA1 = 0.f;

#pragma unroll 2
    for (int ks = 0; ks < 8; ++ks) {
        const int off = ks * 32;
        bf16x8 ah0, al0, ah1, al1, bh0, bl0, bh1, bl1;
        float s0, s1, sd;
        loadcvt(pa0 + off, ah0, al0, s0); sA0 += s0;
        loadcvt(pa1 + off, ah1, al1, s1); sA1 += s1;
        loadcvt(pb0 + off, bh0, bl0, sd);
        loadcvt(pb1 + off, bh1, bl1, sd);

        acc00 = __builtin_amdgcn_mfma_f32_16x16x32_bf16(ah0, bh0, acc00, 0, 0, 0);
        acc00 = __builtin_amdgcn_mfma_f32_16x16x32_bf16(ah0, bl0, acc00, 0, 0, 0);
        acc00 = __builtin_amdgcn_mfma_f32_16x16x32_bf16(al0, bh0, acc00, 0, 0, 0);

        acc01 = __builtin_amdgcn_mfma_f32_16x16x32_bf16(ah0, bh1, acc01, 0, 0, 0);
        acc01 = __builtin_amdgcn_mfma_f32_16x16x32_bf16(ah0, bl1, acc01, 0, 0, 0);
        acc01 = __builtin_amdgcn_mfma_f32_16x16x32_bf16(al0, bh1, acc01, 0, 0, 0);

        acc10 = __builtin_amdgcn_mfma_f32_16x16x32_bf16(ah1, bh0, acc10, 0, 0, 0);
        acc10 = __builtin_amdgcn_mfma_f32_16x16x32_bf16(ah1, bl0, acc10, 0, 0, 0);
        acc10 = __builtin_amdgcn_mfma_f32_16x16x32_bf16(al1, bh0, acc10, 0, 0, 0);

        acc11 = __builtin_amdgcn_mfma_f32_16x16x32_bf16(ah1, bh1, acc11, 0, 0, 0);
        acc11 = __builtin_amdgcn_mfma_f32_16x16x32_bf16(ah1, bl1, acc11, 0, 0, 0);
        acc11 = __builtin_amdgcn_mfma_f32_16x16x32_bf16(al1, bh1, acc11, 0, 0, 0);
    }

    // gpart write: C/D layout col = l&15, row = (l>>4)*4 + reg  [m89-verified]
    float* gp = gpart + (size_t)wg * 4096;
    {
        const int c0 = wc * 32 + lr;
        const int r00 = wr * 32 + lk * 4;
#pragma unroll
        for (int r = 0; r < 4; ++r) {
            gp[(r00 + r) * 64 + c0]           = acc00[r];
            gp[(r00 + r) * 64 + c0 + 16]      = acc01[r];
            gp[(r00 + 16 + r) * 64 + c0]      = acc10[r];
            gp[(r00 + 16 + r) * 64 + c0 + 16] = acc11[r];
        }
    }
    // rowsums: reduce the 4 lk-groups (lanes sharing lr), write from wc==0
    sA0 += __shfl_xor(sA0, 16); sA0 += __shfl_xor(sA0, 32);
    sA1 += __shfl_xor(sA1, 16); sA1 += __shfl_xor(sA1, 32);
    if (wc == 0 && l < 16) {
        float* sp = spart + (size_t)wg * 64 + wr * 32;
        sp[l] = sA0;
        sp[16 + l] = sA1;
    }
}

// ---------------------------------------------------------------------------
// k_gred: G[b] = sum over 256 chunk partials; s[b] likewise.
__global__ __launch_bounds__(256) void k_gred(const float* __restrict__ gpart,
                                              const float* __restrict__ spart,
                                              float* __restrict__ G,
                                              float* __restrict__ s) {
    const int b = blockIdx.x >> 4;
    const int part = blockIdx.x & 15;
    const int t = threadIdx.x;
    const int e4l = t & 63;
    const int cg = t >> 6;                  // wave id 0..3
    const int e4 = part * 64 + e4l;
    const float4* gp4 = (const float4*)gpart;

    float4 a = make_float4(0.f, 0.f, 0.f, 0.f);
#pragma unroll 8
    for (int i = 0; i < 64; ++i) {
        const int w = cg * 64 + i;
        const float4 v = gp4[((size_t)b * 256 + w) * 1024 + e4];
        a.x += v.x; a.y += v.y; a.z += v.z; a.w += v.w;
    }
    __shared__ __align__(16) float4 red[4][64];
    __shared__ float reds[4][64];
    red[cg][e4l] = a;

    float sv = 0.f;
    if (part == 0) {
#pragma unroll 8
        for (int i = 0; i < 64; ++i) {
            const int w = cg * 64 + i;
            sv += spart[((size_t)b * 256 + w) * 64 + e4l];
        }
        reds[cg][e4l] = sv;
    }
    __syncthreads();
    if (cg == 0) {
        const float4 r1 = red[1][e4l], r2 = red[2][e4l], r3 = red[3][e4l];
        float4 o;
        o.x = a.x + r1.x + r2.x + r3.x;
        o.y = a.y + r1.y + r2.y + r3.y;
        o.z = a.z + r1.z + r2.z + r3.z;
        o.w = a.w + r1.w + r2.w + r3.w;
        *(float4*)(G + (size_t)b * 4096 + (size_t)e4 * 4) = o;
        if (part == 0) {
            s[b * 64 + e4l] = sv + reds[1][e4l] + reds[2][e4l] + reds[3][e4l];
        }
    }
}

// ---------------------------------------------------------------------------
// k_small: f = Pw G Tw^T + rank-1 terms; attn = softmax; Mt = (attn@Gw)^T; ab.
__global__ __launch_bounds__(256) void k_small(const float* __restrict__ G,
                                               const float* __restrict__ s,
                                               const float* __restrict__ Pw,
                                               const float* __restrict__ pb,
                                               const float* __restrict__ Tw,
                                               const float* __restrict__ tb,
                                               const float* __restrict__ Gw,
                                               const float* __restrict__ gb,
                                               float* __restrict__ Mt,
                                               float* __restrict__ ab) {
    const int b = blockIdx.x >> 1;
    const int rblk = (blockIdx.x & 1) * 32;
    const int t = threadIdx.x;
    const int rl = t >> 3;
    const int seg = t & 7;
    const int d0 = seg * 8;
    const int rg = rblk + rl;

    __shared__ __align__(16) float GL[64][68];
    __shared__ __align__(16) float TwL[64][68];
    __shared__ __align__(16) float GwL[64][68];
    __shared__ __align__(16) float PwL[32][68];
    __shared__ __align__(16) float AL[32][68];
    __shared__ __align__(16) float atL[32][68];
    __shared__ float sL[64], TsL[64], PsL[32], pbL[64], tbL[64], gbL[64];

    for (int v = t; v < 1024; v += 256) {
        const int k = v >> 4, c4 = (v & 15) * 4;
        *(float4*)&GL[k][c4]  = *(const float4*)(G + (size_t)b * 4096 + (size_t)v * 4);
        *(float4*)&TwL[k][c4] = *(const float4*)(Tw + (size_t)v * 4);
        *(float4*)&GwL[k][c4] = *(const float4*)(Gw + (size_t)v * 4);
    }
    for (int v = t; v < 512; v += 256) {
        const int k = v >> 4, c4 = (v & 15) * 4;
        *(float4*)&PwL[k][c4] = *(const float4*)(Pw + (size_t)(rblk + k) * 64 + c4);
    }
    if (t < 64) {
        sL[t] = s[b * 64 + t];
        pbL[t] = pb[t]; tbL[t] = tb[t]; gbL[t] = gb[t];
    }
    __syncthreads();
    if (t < 64) {
        float a = 0.f;
#pragma unroll 8
        for (int k = 0; k < 64; ++k) a += TwL[t][k] * sL[k];
        TsL[t] = a;
    }
    if (t < 32) {
        float a = 0.f;
#pragma unroll 8
        for (int k = 0; k < 64; ++k) a += PwL[t][k] * sL[k];
        PsL[t] = a;
    }
    {
        float4 a1 = make_float4(0.f, 0.f, 0.f, 0.f), a2 = make_float4(0.f, 0.f, 0.f, 0.f);
#pragma unroll 4
        for (int k = 0; k < 64; ++k) {
            const float pw = PwL[rl][k];
            const float4 g1 = *(const float4*)&GL[k][d0];
            const float4 g2 = *(const float4*)&GL[k][d0 + 4];
            a1.x += pw * g1.x; a1.y += pw * g1.y; a1.z += pw * g1.z; a1.w += pw * g1.w;
            a2.x += pw * g2.x; a2.y += pw * g2.y; a2.z += pw * g2.z; a2.w += pw * g2.w;
        }
        *(float4*)&AL[rl][d0] = a1;
        *(float4*)&AL[rl][d0 + 4] = a2;
    }
    __syncthreads();
    float4 areg[16];
#pragma unroll
    for (int i = 0; i < 16; ++i) areg[i] = *(const float4*)&AL[rl][i * 4];
    float fv[8];
#pragma unroll
    for (int dd = 0; dd < 8; ++dd) {
        const int d = d0 + dd;
        float4 a4 = make_float4(0.f, 0.f, 0.f, 0.f);
#pragma unroll
        for (int i = 0; i < 16; ++i) {
            const float4 tw = *(const float4*)&TwL[d][i * 4];
            a4.x += areg[i].x * tw.x; a4.y += areg[i].y * tw.y;
            a4.z += areg[i].z * tw.z; a4.w += areg[i].w * tw.w;
        }
        const float dot = (a4.x + a4.y) + (a4.z + a4.w);
        fv[dd] = dot + PsL[rl] * tbL[d] + pbL[rg] * (TsL[d] + 65536.f * tbL[d]);
    }
    float mx = fv[0];
#pragma unroll
    for (int dd = 1; dd < 8; ++dd) mx = fmaxf(mx, fv[dd]);
    mx = fmaxf(mx, __shfl_xor(mx, 1));
    mx = fmaxf(mx, __shfl_xor(mx, 2));
    mx = fmaxf(mx, __shfl_xor(mx, 4));
    float sm = 0.f;
#pragma unroll
    for (int dd = 0; dd < 8; ++dd) { fv[dd] = __expf(fv[dd] - mx); sm += fv[dd]; }
    sm += __shfl_xor(sm, 1);
    sm += __shfl_xor(sm, 2);
    sm += __shfl_xor(sm, 4);
    const float inv = 1.f / sm;
    float4 p1, p2;
    p1.x = fv[0] * inv; p1.y = fv[1] * inv; p1.z = fv[2] * inv; p1.w = fv[3] * inv;
    p2.x = fv[4] * inv; p2.y = fv[5] * inv; p2.z = fv[6] * inv; p2.w = fv[7] * inv;
    *(float4*)&atL[rl][d0] = p1;
    *(float4*)&atL[rl][d0 + 4] = p2;
    __syncthreads();
#pragma unroll
    for (int i = 0; i < 16; ++i) areg[i] = *(const float4*)&atL[rl][i * 4];
    float4 m1 = make_float4(0.f, 0.f, 0.f, 0.f), m2 = make_float4(0.f, 0.f, 0.f, 0.f);
    float abv = 0.f;
#pragma unroll
    for (int d4 = 0; d4 < 16; ++d4) {
        const float4 a = areg[d4];
#define MSTEP(comp, dc) { \
        const int d = d4 * 4 + dc; \
        const float ad = a.comp; \
        const float4 g1 = *(const float4*)&GwL[d][d0]; \
        const float4 g2 = *(const float4*)&GwL[d][d0 + 4]; \
        m1.x += ad * g1.x; m1.y += ad * g1.y; m1.z += ad * g1.z; m1.w += ad * g1.w; \
        m2.x += ad * g2.x; m2.y += ad * g2.y; m2.z += ad * g2.z; m2.w += ad * g2.w; \
        abv += ad * gbL[d]; }
        MSTEP(x, 0) MSTEP(y, 1) MSTEP(z, 2) MSTEP(w, 3)
#undef MSTEP
    }
    // store TRANSPOSED: Mt[b][k][r] = (attn@Gw)[r][k]
    float mv[8] = {m1.x, m1.y, m1.z, m1.w, m2.x, m2.y, m2.z, m2.w};
    float* Mb = Mt + (size_t)b * 4096;
#pragma unroll
    for (int dd = 0; dd < 8; ++dd) Mb[(d0 + dd) * 64 + rg] = mv[dd];
    if (seg == 0) ab[b * 64 + rg] = abv;
}

// ---------------------------------------------------------------------------
// k_convV: V[b,o,k,q] = sum_c Ww[o,c] * x[b,k,c*1024+q]   (bf16 out)
// Grid 512 = (b, k, q-half). 4 waves; wave -> 16 o, thread -> 8 q.
__global__ __launch_bounds__(256) void k_convV(const float* __restrict__ x,
                                               const float* __restrict__ WwT,
                                               unsigned short* __restrict__ V) {
    const int bid = blockIdx.x;            // (b<<7)|(k<<1)|qh
    const int b = bid >> 7;
    const int k = (bid >> 1) & 63;
    const int qh = bid & 1;
    const int t = threadIdx.x;
    const int wv = t >> 6;
    const int l = t & 63;
    const int q0 = qh * 512 + l * 8;
    const int o0 = wv * 16;

    __shared__ __align__(16) float WL[64][64];
    {
        const float4* src = (const float4*)WwT;
        float4* dst = (float4*)&WL[0][0];
#pragma unroll
        for (int i = 0; i < 4; ++i) dst[i * 256 + t] = src[i * 256 + t];
    }
    __syncthreads();

    const float* xb = x + ((size_t)b * 64 + k) * 65536 + q0;
    float acc[16][8];
#pragma unroll
    for (int i = 0; i < 16; ++i)
#pragma unroll
        for (int j = 0; j < 8; ++j) acc[i][j] = 0.f;

#pragma unroll 2
    for (int c = 0; c < 64; ++c) {
        const float4 x1 = *(const float4*)(xb + (size_t)c * 1024);
        const float4 x2 = *(const float4*)(xb + (size_t)c * 1024 + 4);
        const float xv[8] = {x1.x, x1.y, x1.z, x1.w, x2.x, x2.y, x2.z, x2.w};
        const float4* wp = (const float4*)&WL[c][o0];
        const float4 w0 = wp[0], w1 = wp[1], w2 = wp[2], w3 = wp[3];
        const float wv16[16] = {w0.x, w0.y, w0.z, w0.w, w1.x, w1.y, w1.z, w1.w,
                                w2.x, w2.y, w2.z, w2.w, w3.x, w3.y, w3.z, w3.w};
#pragma unroll
        for (int i = 0; i < 16; ++i) {
            const float w = wv16[i];
#pragma unroll
            for (int j = 0; j < 8; ++j) acc[i][j] += w * xv[j];
        }
    }
    // store: V[b][o0+i][k][q0..q0+8)  -- fully coalesced uint4 per o
    unsigned short* vb = V + (((size_t)b * 64 + o0) * 64 + k) * 1024 + q0;
#pragma unroll
    for (int i = 0; i < 16; ++i) {
        uint4 pk;
        pk.x = pack2bf(acc[i][0], acc[i][1]);
        pk.y = pack2bf(acc[i][2], acc[i][3]);
        pk.z = pack2bf(acc[i][4], acc[i][5]);
        pk.w = pack2bf(acc[i][6], acc[i][7]);
        *(uint4*)(vb + (size_t)i * 65536) = pk;
    }
}

// ---------------------------------------------------------------------------
// k_wy: w_y[b,o,q*64+r] = sum_k Mt[b,k,r] V[b,o,k,q] + Wsum[o]*ab[b,r] + wb[o]
// Grid 512 = (b, o, q-half). 4 waves; wave -> 16 r, thread -> 8 q.
__global__ __launch_bounds__(256) void k_wy(const unsigned short* __restrict__ V,
                                            const float* __restrict__ Mt,
                                            const float* __restrict__ ab,
                                            const float* __restrict__ Wsum,
                                            const float* __restrict__ wb,
                                            unsigned short* __restrict__ wy,
                                            float* __restrict__ stats) {
    const int bid = blockIdx.x;            // (b<<7)|(o<<1)|qh
    const int b = bid >> 7;
    const int o = (bid >> 1) & 63;
    const int qh = bid & 1;
    const int t = threadIdx.x;
    const int wv = t >> 6;
    const int l = t & 63;
    const int q0 = qh * 512 + l * 8;
    const int r0 = wv * 16;

    __shared__ __align__(16) float MtL[64][64];
    {
        const float4* src = (const float4*)(Mt + (size_t)b * 4096);
        float4* dst = (float4*)&MtL[0][0];
#pragma unroll
        for (int i = 0; i < 4; ++i) dst[i * 256 + t] = src[i * 256 + t];
    }
    __syncthreads();

    const unsigned short* vbase = V + ((size_t)b * 64 + o) * 65536 + q0;
    float acc[16][8];
#pragma unroll
    for (int i = 0; i < 16; ++i)
#pragma unroll
        for (int j = 0; j < 8; ++j) acc[i][j] = 0.f;

#pragma unroll 2
    for (int k = 0; k < 64; ++k) {
        const uint4 u = *(const uint4*)(vbase + (size_t)k * 1024);
        float v[8];
        v[0] = __uint_as_float(u.x << 16);
        v[1] = __uint_as_float(u.x & 0xffff0000u);
        v[2] = __uint_as_float(u.y << 16);
        v[3] = __uint_as_float(u.y & 0xffff0000u);
        v[4] = __uint_as_float(u.z << 16);
        v[5] = __uint_as_float(u.z & 0xffff0000u);
        v[6] = __uint_as_float(u.w << 16);
        v[7] = __uint_as_float(u.w & 0xffff0000u);
        const float4* mp = (const float4*)&MtL[k][r0];
        const float4 m0 = mp[0], m1 = mp[1], m2 = mp[2], m3 = mp[3];
        const float mv16[16] = {m0.x, m0.y, m0.z, m0.w, m1.x, m1.y, m1.z, m1.w,
                                m2.x, m2.y, m2.z, m2.w, m3.x, m3.y, m3.z, m3.w};
#pragma unroll
        for (int i = 0; i < 16; ++i) {
            const float m = mv16[i];
#pragma unroll
            for (int j = 0; j < 8; ++j) acc[i][j] += m * v[j];
        }
    }

    const float wsum_o = Wsum[o];
    const float wb_o = wb[o];
    const float* abb = ab + (size_t)b * 64 + r0;
    float addv[16];
#pragma unroll
    for (int i = 0; i < 16; ++i) addv[i] = wsum_o * abb[i] + wb_o;

    float ssum = 0.f, ssq = 0.f;
#pragma unroll
    for (int i = 0; i < 16; ++i)
#pragma unroll
        for (int j = 0; j < 8; ++j) {
            const float val = acc[i][j] + addv[i];
            acc[i][j] = val;
            ssum += val;
            ssq += val * val;
        }

    // store: for each q (j), 16 consecutive r -> 2x uint4
    unsigned short* wyb = wy + ((size_t)b * 64 + o) * 65536 + (size_t)q0 * 64 + r0;
#pragma unroll
    for (int j = 0; j < 8; ++j) {
        uint4 p1, p2;
        p1.x = pack2bf(acc[0][j],  acc[1][j]);
        p1.y = pack2bf(acc[2][j],  acc[3][j]);
        p1.z = pack2bf(acc[4][j],  acc[5][j]);
        p1.w = pack2bf(acc[6][j],  acc[7][j]);
        p2.x = pack2bf(acc[8][j],  acc[9][j]);
        p2.y = pack2bf(acc[10][j], acc[11][j]);
        p2.z = pack2bf(acc[12][j], acc[13][j]);
        p2.w = pack2bf(acc[14][j], acc[15][j]);
        *(uint4*)(wyb + (size_t)j * 64) = p1;
        *(uint4*)(wyb + (size_t)j * 64 + 8) = p2;
    }

    float v1 = ssum, v2 = ssq;
#pragma unroll
    for (int off = 1; off < 64; off <<= 1) {
        v1 += __shfl_xor(v1, off);
        v2 += __shfl_xor(v2, off);
    }
    if ((t & 63) == 0) {
        atomicAdd(&stats[o], v1);
        atomicAdd(&stats[64 + o], v2);
    }
}

// ---------------------------------------------------------------------------
__global__ __launch_bounds__(64) void k_statfin(const float* __restrict__ stats,
                                                const float* __restrict__ gamma,
                                                const float* __restrict__ beta,
                                                float* __restrict__ scaleA,
                                                float* __restrict__ shiftB) {
    const int o = threadIdx.x;
    const float invn = 1.f / 262144.f;
    const float mean = stats[o] * invn;
    const float var = stats[64 + o] * invn - mean * mean;
    const float sA = gamma[o] * rsqrtf(var + 1e-5f);
    scaleA[o] = sA;
    shiftB[o] = beta[o] - mean * sA;
}

// ---------------------------------------------------------------------------
// k_out: out = wy*scaleA[o] + shiftB[o] + x   (8 elems/thread-iter)
__global__ __launch_bounds__(256) void k_out(const unsigned short* __restrict__ wy,
                                             const float* __restrict__ x,
                                             const float* __restrict__ scaleA,
                                             const float* __restrict__ shiftB,
                                             float* __restrict__ out) {
    const size_t stride = (size_t)gridDim.x * blockDim.x;
    for (size_t i8 = (size_t)blockIdx.x * blockDim.x + threadIdx.x; i8 < 2097152; i8 += stride) {
        const size_t base = i8 * 8;
        const int o = (int)((base >> 16) & 63);
        const uint4 u = *(const uint4*)(wy + base);
        const float4 x1 = *(const float4*)(x + base);
        const float4 x2 = *(const float4*)(x + base + 4);
        const float a = scaleA[o];
        const float c = shiftB[o];
        float4 o1, o2;
        o1.x = __uint_as_float(u.x << 16) * a + c + x1.x;
        o1.y = __uint_as_float(u.x & 0xffff0000u) * a + c + x1.y;
        o1.z = __uint_as_float(u.y << 16) * a + c + x1.z;
        o1.w = __uint_as_float(u.y & 0xffff0000u) * a + c + x1.w;
        o2.x = __uint_as_float(u.z << 16) * a + c + x2.x;
        o2.y = __uint_as_float(u.z & 0xffff0000u) * a + c + x2.y;
        o2.z = __uint_as_float(u.w << 16) * a + c + x2.z;
        o2.w = __uint_as_float(u.w & 0xffff0000u) * a + c + x2.w;
        *(float4*)(out + base) = o1;
        *(float4*)(out + base + 4) = o2;
    }
}

} // namespace

extern "C" void kernel_launch(void* const* d_in, const int* in_sizes, int n_in,
                              void* d_out, int out_size, void* d_ws, size_t ws_size,
                              hipStream_t stream) {
    const float* x        = (const float*)d_in[0];
    const float* theta_w  = (const float*)d_in[1];
    const float* theta_b  = (const float*)d_in[2];
    const float* phi_w    = (const float*)d_in[3];
    const float* phi_b    = (const float*)d_in[4];
    const float* g_w      = (const float*)d_in[5];
    const float* g_b      = (const float*)d_in[6];
    const float* w_w      = (const float*)d_in[7];
    const float* w_b      = (const float*)d_in[8];
    const float* bn_gamma = (const float*)d_in[9];
    const float* bn_beta  = (const float*)d_in[10];
    float* out = (float*)d_out;
    char* ws = (char*)d_ws;

    float* G      = (float*)(ws + OFF_G);
    float* s      = (float*)(ws + OFF_S);
    float* Mt     = (float*)(ws + OFF_M);
    float* ab     = (float*)(ws + OFF_AB);
    float* scaleA = (float*)(ws + OFF_SCALE);
    float* shiftB = scaleA + 64;
    float* stats  = (float*)(ws + OFF_STATS);
    float* WwT    = (float*)(ws + OFF_WWT);
    float* Wsum   = (float*)(ws + OFF_WSUM);
    float* spart  = (float*)(ws + OFF_SPART);
    float* gpart  = (float*)(ws + OFF_GPART);
    unsigned short* V  = (unsigned short*)(ws + OFF_V);
    unsigned short* wy = (unsigned short*)(ws + OFF_WY);

    (void)in_sizes; (void)n_in; (void)out_size; (void)ws_size;

    hipMemsetAsync(stats, 0, 512, stream);
    hipLaunchKernelGGL(k_trans, dim3(1), dim3(256), 0, stream, w_w, WwT, Wsum);
    hipLaunchKernelGGL(k_gram, dim3(1024), dim3(256), 0, stream, x, gpart, spart);
    hipLaunchKernelGGL(k_gred, dim3(64), dim3(256), 0, stream, gpart, spart, G, s);
    hipLaunchKernelGGL(k_small, dim3(8), dim3(256), 0, stream, G, s, phi_w, phi_b,
                       theta_w, theta_b, g_w, g_b, Mt, ab);
    hipLaunchKernelGGL(k_convV, dim3(512), dim3(256), 0, stream, x, WwT, V);
    hipLaunchKernelGGL(k_wy, dim3(512), dim3(256), 0, stream, V, Mt, ab, Wsum, w_b, wy, stats);
    hipLaunchKernelGGL(k_statfin, dim3(1), dim3(64), 0, stream, stats, bn_gamma, bn_beta,
                       scaleA, shiftB);
    hipLaunchKernelGGL(k_out, dim3(2048), dim3(256), 0, stream, wy, x, scaleA, shiftB, out);
}